// Round 1
// baseline (850.092 us; speedup 1.0000x reference)
//
#include <hip/hip_runtime.h>
#include <cstdint>
#include <cstddef>

typedef unsigned long long u64;

// ---------------- prep 1: weight transposes + folded output weights ----------------
__global__ void prep_weights(const float* __restrict__ W1, const float* __restrict__ W2,
                             const float* __restrict__ W3, const float* __restrict__ Wc2,
                             const float* __restrict__ bc2, const float* __restrict__ WA,
                             float* __restrict__ Wt1, float* __restrict__ Wt2,
                             float* __restrict__ Wt3, double* __restrict__ wEff,
                             double* __restrict__ bEff)
{
  int id = blockIdx.x * 256 + (int)threadIdx.x;
  if (id < 65536){ int i = id >> 8, j = id & 255; Wt2[(i<<8)+j] = W2[j*256+i]; }   // W2 (256,256) -> Wt2[i][j]
  if (id < 3072){ int k = id >> 8, j = id & 255; Wt1[(k<<8)+j] = W1[j*12+k]; }     // W1 (256,12) -> Wt1[k][j]
  if (id < 1024){ int i = id >> 2, jj = id & 3; Wt3[id] = (jj<3) ? W3[jj*256+i] : 0.0f; } // W3 (6,256) -> Wt3[i][0..2]
  if (id < 32){ double s = 0.0; for (int c=0;c<64;c++) s += (double)WA[c]*(double)Wc2[c*32+id]; wEff[id] = s; }
  if (id == 32){ double s = 0.0; for (int c=0;c<64;c++) s += (double)WA[c]*(double)bc2[c]; *bEff = s; }
}

// ---------------- prep 2: rate-encode probabilities (f64, matches np-f64 pipeline) ----------------
__global__ void prep_probs(const float* __restrict__ x, double* __restrict__ probs, int B)
{
  int b = blockIdx.x, k = (int)threadIdx.x;
  if (b >= B || k >= 24) return;
  double* pb = probs + (size_t)b*24;
  if (k >= 18){ pb[k] = -1.0; return; }  // padding: never fires
  int fk, g0, gn;
  if (k < 12){ fk = k;          g0 = 0;  gn = 12; }  // spk_in: x[:, 0:12]
  else if (k < 15){ fk = 6+(k-12);  g0 = 6;  gn = 6; }  // spk_thdot: x[:, 6:12], h=0..2
  else           { fk = 12+(k-15); g0 = 12; gn = 6; }  // spk_thdot2: x[:,12:18], h=0..2
  const float* xb = x + (size_t)b*18;
  double mn = (double)xb[g0], mx = mn;
  for (int f = 1; f < gn; f++){ double v = (double)xb[g0+f]; mn = fmin(mn, v); mx = fmax(mx, v); }
  double rng = mx - mn; if (rng == 0.0) rng = 1.0;
  double norm = ((double)xb[fk] - mn) / rng;
  double p = (100.0 * norm) * 0.001;
  p = fmin(fmax(p, 0.0), 1.0);
  pb[k] = p;
}

// ---------------- prep 3: pack all input spike bits into one u32 per (t,b) ----------------
__global__ void prep_enc(const float* __restrict__ u1, const float* __restrict__ u2,
                         const float* __restrict__ u3, const double* __restrict__ probs,
                         unsigned* __restrict__ enc, int B)
{
  int b = blockIdx.x * blockDim.x + (int)threadIdx.x;
  int t = blockIdx.y;
  if (b >= B) return;
  const double* pb = probs + (size_t)b*24;
  size_t r = (size_t)t * B + b;
  const float* a1 = u1 + r*12;
  const float* a2 = u2 + r*6;
  const float* a3 = u3 + r*6;
  unsigned e = 0;
  #pragma unroll
  for (int k = 0; k < 12; k++) if ((double)a1[k] < pb[k])    e |= (1u << k);
  #pragma unroll
  for (int h = 0; h < 3; h++)  if ((double)a2[h] < pb[12+h]) e |= (1u << (12+h));
  #pragma unroll
  for (int h = 0; h < 3; h++)  if ((double)a3[h] < pb[15+h]) e |= (1u << (15+h));
  enc[r] = e;
}

// ---------------- main: one wave per batch row, 200-step serial LIF chain ----------------
// Lane l owns neurons j = 4l..4l+3 of layers 1&2 (float4 row loads from Wt1/Wt2).
// Spike masks are wave-uniform (ballot -> SGPR); sparse scalar ctz loops, unroll x4.
__global__ __launch_bounds__(256) void snn_main(
    const unsigned* __restrict__ enc,
    const float* __restrict__ b1, const float* __restrict__ b2, const float* __restrict__ b3,
    const float* __restrict__ Wc1, const float* __restrict__ bc1,
    const float* __restrict__ Wt1, const float* __restrict__ Wt2, const float* __restrict__ Wt3,
    const double* __restrict__ wEff, const double* __restrict__ bEff,
    float* __restrict__ out, int B, int T)
{
  const int lane = (int)(threadIdx.x & 63);
  const int b = blockIdx.x * 4 + (int)(threadIdx.x >> 6);
  if (b >= B) return;
  const int l4 = lane << 2;

  const float4 b1f = *(const float4*)(b1 + l4);
  const float4 b2f = *(const float4*)(b2 + l4);
  const double b1d0=b1f.x, b1d1=b1f.y, b1d2=b1f.z, b1d3=b1f.w;
  const double b2d0=b2f.x, b2d1=b2f.y, b2d2=b2f.z, b2d3=b2f.w;
  const double b3d = (lane < 3) ? (double)b3[lane] : 0.0;
  double wc1a=0.0, wc1b=0.0, wc1c=0.0, bc1d=0.0, wEd=0.0;
  if (lane < 32){
    wc1a = (double)Wc1[lane*3+0];   // channel 0: s_td
    wc1b = (double)Wc1[lane*3+1];   // channel 1: spk3
    wc1c = (double)Wc1[lane*3+2];   // channel 2: s_td2
    bc1d = (double)bc1[lane];
    wEd  = wEff[lane];
  }
  const float* __restrict__ w1base = Wt1 + l4;
  const float* __restrict__ w2base = Wt2 + l4;

  double m10=0,m11=0,m12=0,m13=0;     // layer1 mem (j=4l+c)
  double m20=0,m21=0,m22=0,m23=0;     // layer2 mem
  double m3v=0;                       // layer3 mem (lane<3 -> j=lane)
  double m40=0,m41=0,m42=0;           // layer4 mem (o=lane<32, h=0..2)

  for (int t = 0; t < T; t++){
    const unsigned e = enc[(size_t)t * B + b];
    const unsigned sm  = e & 0xFFFu;
    const unsigned td  = (e >> 12) & 7u;
    const unsigned td2 = (e >> 15) & 7u;

    // ---- layer 1: cur1 = b1 + sum over active input bits ----
    double c0=b1d0, c1=b1d1, c2=b1d2, c3=b1d3;
    {
      unsigned w = sm;
      while (w){
        int k0 = __builtin_ctz(w); w &= w-1;
        int k1=k0,k2=k0,k3=k0,n=1;
        if (w){ k1=__builtin_ctz(w); w&=w-1; n=2;
          if (w){ k2=__builtin_ctz(w); w&=w-1; n=3;
            if (w){ k3=__builtin_ctz(w); w&=w-1; n=4; } } }
        const float4 r0 = *(const float4*)(w1base + (k0<<8));
        const float4 r1 = *(const float4*)(w1base + (k1<<8));
        const float4 r2 = *(const float4*)(w1base + (k2<<8));
        const float4 r3 = *(const float4*)(w1base + (k3<<8));
        c0 += (double)r0.x; c1 += (double)r0.y; c2 += (double)r0.z; c3 += (double)r0.w;
        if (n>1){ c0+=(double)r1.x; c1+=(double)r1.y; c2+=(double)r1.z; c3+=(double)r1.w; }
        if (n>2){ c0+=(double)r2.x; c1+=(double)r2.y; c2+=(double)r2.z; c3+=(double)r2.w; }
        if (n>3){ c0+=(double)r3.x; c1+=(double)r3.y; c2+=(double)r3.z; c3+=(double)r3.w; }
      }
    }
    bool rr;
    rr = m10>1.0; m10 = 0.9*m10 + c0; if (rr) m10 -= 1.0;
    rr = m11>1.0; m11 = 0.9*m11 + c1; if (rr) m11 -= 1.0;
    rr = m12>1.0; m12 = 0.9*m12 + c2; if (rr) m12 -= 1.0;
    rr = m13>1.0; m13 = 0.9*m13 + c3; if (rr) m13 -= 1.0;
    const u64 s1w0 = __ballot(m10 > 1.0);
    const u64 s1w1 = __ballot(m11 > 1.0);
    const u64 s1w2 = __ballot(m12 > 1.0);
    const u64 s1w3 = __ballot(m13 > 1.0);

    // ---- layer 2: sparse over active spk1 (i = 4*bitpos + cw) ----
    c0=b2d0; c1=b2d1; c2=b2d2; c3=b2d3;
#define L2LOOP(WREG, CW) { u64 w = (WREG); \
      while (w){ \
        int i0 = ((int)__builtin_ctzll(w)<<2)+(CW); w &= w-1; \
        int i1=i0,i2=i0,i3=i0,n=1; \
        if (w){ i1=((int)__builtin_ctzll(w)<<2)+(CW); w&=w-1; n=2; \
          if (w){ i2=((int)__builtin_ctzll(w)<<2)+(CW); w&=w-1; n=3; \
            if (w){ i3=((int)__builtin_ctzll(w)<<2)+(CW); w&=w-1; n=4; } } } \
        const float4 r0 = *(const float4*)(w2base + (i0<<8)); \
        const float4 r1 = *(const float4*)(w2base + (i1<<8)); \
        const float4 r2 = *(const float4*)(w2base + (i2<<8)); \
        const float4 r3 = *(const float4*)(w2base + (i3<<8)); \
        c0 += (double)r0.x; c1 += (double)r0.y; c2 += (double)r0.z; c3 += (double)r0.w; \
        if (n>1){ c0+=(double)r1.x; c1+=(double)r1.y; c2+=(double)r1.z; c3+=(double)r1.w; } \
        if (n>2){ c0+=(double)r2.x; c1+=(double)r2.y; c2+=(double)r2.z; c3+=(double)r2.w; } \
        if (n>3){ c0+=(double)r3.x; c1+=(double)r3.y; c2+=(double)r3.z; c3+=(double)r3.w; } \
      } }
    L2LOOP(s1w0, 0)
    L2LOOP(s1w1, 1)
    L2LOOP(s1w2, 2)
    L2LOOP(s1w3, 3)

    rr = m20>1.0; m20 = 0.9*m20 + c0; if (rr) m20 -= 1.0;
    rr = m21>1.0; m21 = 0.9*m21 + c1; if (rr) m21 -= 1.0;
    rr = m22>1.0; m22 = 0.9*m22 + c2; if (rr) m22 -= 1.0;
    rr = m23>1.0; m23 = 0.9*m23 + c3; if (rr) m23 -= 1.0;
    const u64 s2w0 = __ballot(m20 > 1.0);
    const u64 s2w1 = __ballot(m21 > 1.0);
    const u64 s2w2 = __ballot(m22 > 1.0);
    const u64 s2w3 = __ballot(m23 > 1.0);

    // ---- layer 3 (only j=0..2 feed the conv): sparse over active spk2 ----
    double cl3 = b3d;
#define L3LOOP(WREG, CW) { u64 w = (WREG); \
      while (w){ \
        int i0 = ((int)__builtin_ctzll(w)<<2)+(CW); w &= w-1; \
        int i1=i0,i2=i0,i3=i0,n=1; \
        if (w){ i1=((int)__builtin_ctzll(w)<<2)+(CW); w&=w-1; n=2; \
          if (w){ i2=((int)__builtin_ctzll(w)<<2)+(CW); w&=w-1; n=3; \
            if (w){ i3=((int)__builtin_ctzll(w)<<2)+(CW); w&=w-1; n=4; } } } \
        float q0=0.f,q1=0.f,q2=0.f,q3=0.f; \
        if (lane < 3){ q0 = Wt3[(i0<<2)+lane]; q1 = Wt3[(i1<<2)+lane]; \
                       q2 = Wt3[(i2<<2)+lane]; q3 = Wt3[(i3<<2)+lane]; } \
        cl3 += (double)q0; \
        if (n>1) cl3 += (double)q1; \
        if (n>2) cl3 += (double)q2; \
        if (n>3) cl3 += (double)q3; \
      } }
    L3LOOP(s2w0, 0)
    L3LOOP(s2w1, 1)
    L3LOOP(s2w2, 2)
    L3LOOP(s2w3, 3)

    rr = m3v>1.0; m3v = 0.9*m3v + cl3; if (rr) m3v -= 1.0;
    const unsigned s3 = (unsigned)(__ballot((lane < 3) && (m3v > 1.0)) & 7ull);

    // ---- layer 4 (conv1 LIF): lane<32 = out-channel o, h = 0..2 ----
    double cur;
    cur = bc1d; if (td  & 1u) cur += wc1a; if (s3 & 1u) cur += wc1b; if (td2 & 1u) cur += wc1c;
    rr = m40>1.0; m40 = 0.9*m40 + cur; if (rr) m40 -= 1.0;
    cur = bc1d; if (td  & 2u) cur += wc1a; if (s3 & 2u) cur += wc1b; if (td2 & 2u) cur += wc1c;
    rr = m41>1.0; m41 = 0.9*m41 + cur; if (rr) m41 -= 1.0;
    cur = bc1d; if (td  & 4u) cur += wc1a; if (s3 & 4u) cur += wc1b; if (td2 & 4u) cur += wc1c;
    rr = m42>1.0; m42 = 0.9*m42 + cur; if (rr) m42 -= 1.0;
  }

  // ---- output: out[b,m] = bEff + sum_o spk4_final[o,m] * wEff[o] ----
  double o0 = (lane < 32 && m40 > 1.0) ? wEd : 0.0;
  double o1 = (lane < 32 && m41 > 1.0) ? wEd : 0.0;
  double o2 = (lane < 32 && m42 > 1.0) ? wEd : 0.0;
  for (int off = 32; off > 0; off >>= 1){
    o0 += __shfl_xor(o0, off, 64);
    o1 += __shfl_xor(o1, off, 64);
    o2 += __shfl_xor(o2, off, 64);
  }
  if (lane == 0){
    const double be = *bEff;
    out[b*3+0] = (float)(o0 + be);
    out[b*3+1] = (float)(o1 + be);
    out[b*3+2] = (float)(o2 + be);
  }
}

// ---------------- host ----------------
extern "C" void kernel_launch(void* const* d_in, const int* in_sizes, int n_in,
                              void* d_out, int out_size, void* d_ws, size_t ws_size,
                              hipStream_t stream)
{
  const float* x   = (const float*)d_in[0];
  const float* u1  = (const float*)d_in[1];
  const float* u2  = (const float*)d_in[2];
  const float* u3  = (const float*)d_in[3];
  const float* W1  = (const float*)d_in[4];
  const float* b1  = (const float*)d_in[5];
  const float* W2  = (const float*)d_in[6];
  const float* b2  = (const float*)d_in[7];
  const float* W3  = (const float*)d_in[8];
  const float* b3  = (const float*)d_in[9];
  const float* Wc1 = (const float*)d_in[10];
  const float* bc1 = (const float*)d_in[11];
  const float* Wc2 = (const float*)d_in[12];
  const float* bc2 = (const float*)d_in[13];
  const float* WA  = (const float*)d_in[14];
  float* out = (float*)d_out;

  const int B = in_sizes[0] / 18;
  const int T = in_sizes[1] / (B * 12);

  char* ws = (char*)d_ws;
  float*  Wt2   = (float*)(ws + 0);                        // 256*256*4 = 262144
  float*  Wt1   = (float*)(ws + 262144);                   // 12*256*4  = 12288
  float*  Wt3   = (float*)(ws + 274432);                   // 256*4*4   = 4096
  double* wEff  = (double*)(ws + 278528);                  // 32*8      = 256
  double* bEff  = (double*)(ws + 278784);                  // 8
  double* probs = (double*)(ws + 278792);                  // B*24*8
  unsigned* enc = (unsigned*)(ws + 278792 + (size_t)B*24*8); // T*B*4

  hipLaunchKernelGGL(prep_weights, dim3(256), dim3(256), 0, stream,
                     W1, W2, W3, Wc2, bc2, WA, Wt1, Wt2, Wt3, wEff, bEff);
  hipLaunchKernelGGL(prep_probs, dim3(B), dim3(64), 0, stream, x, probs, B);
  hipLaunchKernelGGL(prep_enc, dim3((B+255)/256, T), dim3(256), 0, stream,
                     u1, u2, u3, probs, enc, B);
  hipLaunchKernelGGL(snn_main, dim3((B+3)/4), dim3(256), 0, stream,
                     enc, b1, b2, b3, Wc1, bc1, Wt1, Wt2, Wt3, wEff, bEff, out, B, T);
}